// Round 11
// baseline (272.129 us; speedup 1.0000x reference)
//
#include <hip/hip_runtime.h>
#include <math.h>

#define EMBED 1024
#define NHEAD 16
#define HDIM  64
#define BATCH 4
#define SEQ   2048
#define MROWS (BATCH * SEQ)   // 8192

typedef __attribute__((ext_vector_type(4))) short short4v;
typedef __attribute__((ext_vector_type(8))) short short8;
typedef __attribute__((ext_vector_type(4))) float floatx4;
typedef __attribute__((ext_vector_type(16))) float floatx16;
typedef __attribute__((ext_vector_type(2))) unsigned uint2v;

#if __has_builtin(__builtin_amdgcn_exp2f)
#define EXP2(x) __builtin_amdgcn_exp2f(x)
#else
#define EXP2(x) exp2f(x)
#endif

// RNE float -> bf16 (finite inputs only).
__device__ __forceinline__ unsigned short f2bf(float f) {
  unsigned u = __float_as_uint(f);
  u += 0x7fffu + ((u >> 16) & 1u);
  return (unsigned short)(u >> 16);
}

#if __has_builtin(__builtin_amdgcn_cvt_pk_bf16_f32)
__device__ __forceinline__ unsigned pack2bf(float lo, float hi) {
  typedef __attribute__((ext_vector_type(2))) __bf16 bf2;
  union { bf2 b; unsigned u; } c;
  c.b = __builtin_amdgcn_cvt_pk_bf16_f32(lo, hi);
  return c.u;
}
#else
__device__ __forceinline__ unsigned pack2bf(float lo, float hi) {
  return ((__float_as_uint(lo) + 0x8000u) >> 16) |
         ((__float_as_uint(hi) + 0x8000u) & 0xffff0000u);
}
#endif

__device__ __forceinline__ uint2v pl32swap(unsigned a, unsigned b) {
#if __has_builtin(__builtin_amdgcn_permlane32_swap)
  return __builtin_amdgcn_permlane32_swap(a, b, false, false);
#else
  uint2v r;
  unsigned ax = (unsigned)__shfl_xor((int)a, 32);
  unsigned bx = (unsigned)__shfl_xor((int)b, 32);
  const int hi = (int)((threadIdx.x & 63) >> 5);
  r[0] = hi ? bx : a;
  r[1] = hi ? b : ax;
  return r;
#endif
}

// Async global->LDS, 16 B per lane. lds dest MUST be wave-uniform base;
// HW adds lane*16.
__device__ __forceinline__ void gl_lds16(const void* g, void* l) {
  __builtin_amdgcn_global_load_lds(
      (const __attribute__((address_space(1))) unsigned int*)g,
      (__attribute__((address_space(3))) unsigned int*)l, 16, 0, 0);
}

// ---------------------------------------------------------------------------
// Cast fp32 -> bf16: x (8M elems) + 4 weights (1M each, contiguous dst).
// ---------------------------------------------------------------------------
__global__ __launch_bounds__(256) void cast_bf16_kernel(
    const float* __restrict__ x,  const float* __restrict__ wq,
    const float* __restrict__ wk, const float* __restrict__ wv,
    const float* __restrict__ wo,
    unsigned short* __restrict__ xb, unsigned short* __restrict__ wb) {
  const size_t NX = (size_t)MROWS * EMBED;                 // 2^23
  size_t i4 = ((size_t)blockIdx.x * 256 + threadIdx.x) * 4;
  const float* src;
  unsigned short* dst;
  size_t off;
  if (i4 < NX) {
    src = x; dst = xb; off = i4;
  } else {
    size_t j = i4 - NX;
    int r = (int)(j >> 20);
    off = j & ((1u << 20) - 1);
    src = (r == 0) ? wq : (r == 1) ? wk : (r == 2) ? wv : wo;
    dst = wb + ((size_t)r << 20);
  }
  float4 v = *(const float4*)(src + off);
  ushort4 o;
  o.x = f2bf(v.x); o.y = f2bf(v.y); o.z = f2bf(v.z); o.w = f2bf(v.w);
  *(ushort4*)(dst + off) = o;
}

// ---------------------------------------------------------------------------
// R18: 256x256 8-phase bf16 GEMM core (T3+T4+T2+T5 port, learn_hip m201
// structure). 8 waves (2Mx4N), per-wave output 128x64, BK=64, LDS 128KB =
// {A,B} x 2buf x 2half x [128][64]. Per iteration: 2 K-tiles, 8 phases;
// each phase: {ds-read frags | stage ONE half-tile (2 gl_lds) | barrier |
// lgkmcnt(0) | 16 MFMA in setprio(1)}. Counted s_waitcnt vmcnt(6) ONLY at
// phases 0 and 4 (stage-then-gate; retires the tile about to be read,
// keeps 3 half-tiles in flight). XOR-8 16B-group swizzle on LDS rows
// (proven in attn's Ks, identical 128B-row geometry): write side via
// pre-swizzled global source (gl_lds dest linear), read side same XOR.
// Stage schedule per iteration (derived, WAR/FIFO hand-verified):
//   p0: A(T+1)h0  p1: A(T+1)h1  p2: B(T+2)h0  p3: B(T+2)h1
//   p4: A(T+2)h0  p5: A(T+2)h1  p6: B(T+3)h0  p7: B(T+3)h1
// Prologue stages A(0),B(0),B(1); tail stages wrap (t&15), never read.
// ---------------------------------------------------------------------------
#define RD_A(bo, mi, ks) (*(const short8*)&LA[(bo) + wr * 8192 + \
    ((mi) * 16 + l15) * 64 + ((((ks) * 4 + quad) ^ (l15 & 7)) * 8)])
#define RD_B(bo, ni, ks) (*(const short8*)&LB[(bo) + hB * 8192 + \
    (rB0 + (ni) * 16 + l15) * 64 + ((((ks) * 4 + quad) ^ (l15 & 7)) * 8)])

__device__ __forceinline__ void gemm_core8(
    const unsigned short* __restrict__ Amat,
    const unsigned short* __restrict__ Bmat,
    int mBase, int nBase,
    unsigned short* LA, unsigned short* LB,
    floatx4 acc[8][4]) {
  const int t = threadIdx.x;                 // 0..511
  const int lane = t & 63, wv = t >> 6;      // 8 waves
  const int wr = wv >> 2, wc = wv & 3;
  const int quad = lane >> 4, l15 = lane & 15;
  const int hB = wc >> 1, rB0 = (wc & 1) * 64;

  // Staging addresses. Chunk c = i*512 + t covers LDS bytes [c*16,c*16+16)
  // of a half-tile; stored 16B-group (c&7) holds logical group
  // (c&7)^(row&7) -> pre-swizzled global source, linear LDS dest.
  const unsigned short* sA[2][2];
  const unsigned short* sB[2][2];
  unsigned short* dA[2][2];
  unsigned short* dB[2][2];
#pragma unroll
  for (int h = 0; h < 2; ++h)
#pragma unroll
    for (int i = 0; i < 2; ++i) {
      const int c = i * 512 + t;
      const int row = c >> 3, g = (c & 7) ^ (row & 7);
      sA[h][i] = Amat + (size_t)(mBase + h * 128 + row) * EMBED + g * 8;
      sB[h][i] = Bmat + (size_t)(nBase + h * 128 + row) * EMBED + g * 8;
      const int du = h * 8192 + (i * 512 + wv * 64) * 8;   // wave-uniform
      dA[h][i] = LA + du;
      dB[h][i] = LB + du;
    }

  // Prologue: A(0), B(0) -> buf0; B(1) -> buf1. 12 loads, no wait (the
  // first p0 vmcnt(6) retires A(0),B(0) and keeps B(1)+A(1)h0 in flight).
  gl_lds16(sA[0][0], dA[0][0]); gl_lds16(sA[0][1], dA[0][1]);
  gl_lds16(sA[1][0], dA[1][0]); gl_lds16(sA[1][1], dA[1][1]);
  gl_lds16(sB[0][0], dB[0][0]); gl_lds16(sB[0][1], dB[0][1]);
  gl_lds16(sB[1][0], dB[1][0]); gl_lds16(sB[1][1], dB[1][1]);
  gl_lds16(sB[0][0] + 64, dB[0][0] + 16384);
  gl_lds16(sB[0][1] + 64, dB[0][1] + 16384);
  gl_lds16(sB[1][0] + 64, dB[1][0] + 16384);
  gl_lds16(sB[1][1] + 64, dB[1][1] + 16384);

  short8 b[4][2];
  for (int T = 0; T < 16; T += 2) {          // 8 iterations, 2 K-tiles each
#pragma unroll
    for (int hf = 0; hf < 2; ++hf) {         // hf0: tile T buf0; hf1: T+1 buf1
      const int bo = hf * 16384;
#pragma unroll
      for (int p = 0; p < 4; ++p) {
        short8 a[2][2];
        if (p == 0) {
          // stage A(T+1+hf)h0, then gate, then read this tile's frags.
          {
            const int ts = (T + 1 + hf) & 15, tb = (ts & 1) * 16384;
            gl_lds16(sA[0][0] + (size_t)ts * 64, dA[0][0] + tb);
            gl_lds16(sA[0][1] + (size_t)ts * 64, dA[0][1] + tb);
          }
          asm volatile("s_waitcnt vmcnt(6)" ::: "memory");
          __builtin_amdgcn_sched_barrier(0);
          __builtin_amdgcn_s_barrier();      // all waves' loads retired
#pragma unroll
          for (int ni = 0; ni < 4; ++ni) {
            b[ni][0] = RD_B(bo, ni, 0);
            b[ni][1] = RD_B(bo, ni, 1);
          }
          a[0][0] = RD_A(bo, 0, 0); a[0][1] = RD_A(bo, 0, 1);
          a[1][0] = RD_A(bo, 1, 0); a[1][1] = RD_A(bo, 1, 1);
        } else {
          const int mi0 = 2 * p;
          a[0][0] = RD_A(bo, mi0, 0);     a[0][1] = RD_A(bo, mi0, 1);
          a[1][0] = RD_A(bo, mi0 + 1, 0); a[1][1] = RD_A(bo, mi0 + 1, 1);
          if (p == 1) {
            const int ts = (T + 1 + hf) & 15, tb = (ts & 1) * 16384;
            gl_lds16(sA[1][0] + (size_t)ts * 64, dA[1][0] + tb);
            gl_lds16(sA[1][1] + (size_t)ts * 64, dA[1][1] + tb);
          } else if (p == 2) {
            const int ts = (T + 2 + hf) & 15, tb = (ts & 1) * 16384;
            gl_lds16(sB[0][0] + (size_t)ts * 64, dB[0][0] + tb);
            gl_lds16(sB[0][1] + (size_t)ts * 64, dB[0][1] + tb);
          } else {
            const int ts = (T + 2 + hf) & 15, tb = (ts & 1) * 16384;
            gl_lds16(sB[1][0] + (size_t)ts * 64, dB[1][0] + tb);
            gl_lds16(sB[1][1] + (size_t)ts * 64, dB[1][1] + tb);
          }
          __builtin_amdgcn_sched_barrier(0);
          __builtin_amdgcn_s_barrier();
        }
        asm volatile("s_waitcnt lgkmcnt(0)" ::: "memory");
        __builtin_amdgcn_sched_barrier(0);
        __builtin_amdgcn_s_setprio(1);
        const int mi0 = 2 * p;
#pragma unroll
        for (int m2 = 0; m2 < 2; ++m2)
#pragma unroll
          for (int ni = 0; ni < 4; ++ni) {
            acc[mi0 + m2][ni] = __builtin_amdgcn_mfma_f32_16x16x32_bf16(
                a[m2][0], b[ni][0], acc[mi0 + m2][ni], 0, 0, 0);
            acc[mi0 + m2][ni] = __builtin_amdgcn_mfma_f32_16x16x32_bf16(
                a[m2][1], b[ni][1], acc[mi0 + m2][ni], 0, 0, 0);
          }
        __builtin_amdgcn_s_setprio(0);
        __builtin_amdgcn_sched_barrier(0);
        __builtin_amdgcn_s_barrier();        // frees this phase's WAR slot
      }
    }
  }
  asm volatile("s_waitcnt vmcnt(0)" ::: "memory");  // drain wrapped stages
}

// ---------------------------------------------------------------------------
// QKV projection as ONE GEMM: A[8192,1024] @ Wstack[3072,1024]^T (wq,wk,wv
// are contiguous in wb). Q pre-scaled by (1/8)*log2(e). Q,K out: [b,h,s,d];
// V out: [b,h,d,s]. 384 blocks, bijective XCD decode (B-panel shared by
// consecutive blocks, per-XCD A chunk 2MB L2-resident).
// ---------------------------------------------------------------------------
__global__ __launch_bounds__(512, 2) void proj_qkv_bf16(
    const unsigned short* __restrict__ xb,
    const unsigned short* __restrict__ wb,
    unsigned short* __restrict__ qkv) {
  const int id = blockIdx.x;                 // 0..383
  const int xcd = id & 7;
  const int r = id >> 3;                     // 0..47
  const int nIdx = r >> 2;                   // 0..11
  const int mBase = (xcd * 4 + (r & 3)) * 256;
  const int nBase = nIdx * 256;

  __shared__ unsigned short LA[32768];       // 64 KB
  __shared__ unsigned short LB[32768];       // 64 KB

  floatx4 acc[8][4] = {};
  gemm_core8(xb, wb, mBase, nBase, LA, LB, acc);

  const int t = threadIdx.x;
  const int lane = t & 63, wv = t >> 6;
  const int wr = wv >> 2, wc = wv & 3;
  const int quad = lane >> 4, l15 = lane & 15;

  const int which = nBase >> 10;             // uniform per block (256|1024)
  const int nloc0 = nBase & 1023;
  unsigned short* out = qkv + (size_t)which * MROWS * EMBED;

  if (which < 2) {
    const float scale = (which == 0) ? 0.18033688f : 1.0f;  // (1/8)*log2(e)
#pragma unroll
    for (int mi = 0; mi < 8; ++mi)
#pragma unroll
      for (int ni = 0; ni < 4; ++ni) {
        const int nn = nloc0 + wc * 64 + ni * 16 + l15;
        const int h = nn >> 6, d = nn & 63;
#pragma unroll
        for (int r2 = 0; r2 < 4; ++r2) {
          const int m = mBase + wr * 128 + mi * 16 + quad * 4 + r2;
          const int b = m >> 11, s = m & (SEQ - 1);
          out[(((size_t)(b * NHEAD + h) * SEQ) + s) * HDIM + d] =
              f2bf(acc[mi][ni][r2] * scale);
        }
      }
  } else {
    // V^T: [b,h,d,s] — 4 consecutive s per lane -> packed 8 B store.
#pragma unroll
    for (int mi = 0; mi < 8; ++mi) {
      const int m0 = mBase + wr * 128 + mi * 16 + quad * 4;
      const int b = m0 >> 11, s0 = m0 & (SEQ - 1);
#pragma unroll
      for (int ni = 0; ni < 4; ++ni) {
        const int nn = nloc0 + wc * 64 + ni * 16 + l15;
        const int h = nn >> 6, d = nn & 63;
        ushort4 pk;
        pk.x = f2bf(acc[mi][ni][0]); pk.y = f2bf(acc[mi][ni][1]);
        pk.z = f2bf(acc[mi][ni][2]); pk.w = f2bf(acc[mi][ni][3]);
        *(ushort4*)&out[((size_t)(b * NHEAD + h) * HDIM + d) * SEQ + s0] = pk;
      }
    }
  }
}

// ---------------------------------------------------------------------------
// MFMA flash attention, transposed-score formulation.
// = R12 structure (best measured: 85.6-87.0us). R13 (interleave), R14
// (domain decorrelation) and R15 (split-K, cache collapse) all failed to
// beat it — phase-separated 2-blocks/CU with KVBLK=128 is the optimum.
// ---------------------------------------------------------------------------
__global__ __launch_bounds__(256, 2) void attn_mfma(
    const unsigned short* __restrict__ qkv,
    unsigned short* __restrict__ aout) {
  const unsigned short* Q = qkv;
  const unsigned short* K = qkv + (size_t)MROWS * EMBED;
  const unsigned short* V = qkv + 2 * (size_t)MROWS * EMBED;

  // XCD-locality decode: all 8 q-blocks of one bh land on one XCD.
  const int id = blockIdx.x;
  const int xcd = id & 7, slot = id >> 3;      // slot 0..63
  const int bh = xcd * 8 + (slot >> 3);
  const int qBase = (slot & 7) * 256;

  __shared__ unsigned short Ks[2 * 128 * 64];  // [buf][key][d], XOR-8 swizzled
  __shared__ unsigned short Vs[2 * 64 * 128];  // [buf][d][key], XOR-16 swizzled

  const int t = threadIdx.x;
  const int lane = t & 63, w = t >> 6;         // w 0..3
  const int h2 = lane >> 5;     // lane half (k-group selector in A/B frags)
  const int q31 = lane & 31;    // query within group / col within MFMA tile

  // Q B-frags (pre-scaled by (1/8)*log2e): B[k=d][n=q]. Two query groups.
  const unsigned short* qrowA =
      Q + ((size_t)bh * SEQ + qBase + w * 64 + q31) * HDIM;
  const unsigned short* qrowB = qrowA + 32 * HDIM;
  short8 qaA[4], qaB[4];
#pragma unroll
  for (int ds = 0; ds < 4; ++ds) {
    qaA[ds] = *(const short8*)(qrowA + ds * 16 + h2 * 8);
    qaB[ds] = *(const short8*)(qrowB + ds * 16 + h2 * 8);
  }

  // Staging: 256 threads stage 16 KB K + 16 KB V per tile -> 4 K-chunks +
  // 4 V-chunks of 16 B per thread (8 gl_lds per tile).
  const unsigned short* kbase = K + (size_t)bh * SEQ * HDIM;
  const unsigned short* vbase = V + (size_t)bh * HDIM * SEQ;
  const unsigned short* gk[4];
  const unsigned short* gv[4];
  unsigned short* lk[4];
  unsigned short* lv[4];
#pragma unroll
  for (int i = 0; i < 4; ++i) {
    const int c = i * 256 + t;                 // per-lane chunk 0..1023
    const int krow = c >> 3, kgrp = (c & 7) ^ (krow & 7);
    gk[i] = kbase + (size_t)krow * HDIM + kgrp * 8;
    const int vd = c >> 4, vj = (c & 15) ^ (vd & 15);
    gv[i] = vbase + (size_t)vd * SEQ + vj * 8;
    const int cu = i * 256 + w * 64;           // wave-uniform chunk base
    lk[i] = Ks + cu * 8;
    lv[i] = Vs + cu * 8;
  }

  floatx16 otA0 = {}, otA1 = {};  // group A O^T accum: d 0-31, 32-63
  floatx16 otB0 = {}, otB1 = {};  // group B
  float laccA = 0.0f, laccB = 0.0f;

  // Prologue: stage tile 0 into buffer 0.
#pragma unroll
  for (int i = 0; i < 4; ++i) {
    gl_lds16(gk[i], lk[i]);
    gl_lds16(gv[i], lv[i]);
  }

  for (int kt = 0; kt < SEQ; kt += 128) {
    const int cb = (kt >> 7) & 1;              // current buffer
    const int nb = cb ^ 1;                     // prefetch buffer
    const int nxt = (kt + 128) & (SEQ - 1);    // last iter re-stages tile 0
                                               // (keeps vmcnt count uniform)
    const int sOff = nb * 8192;                // ushort offset of prefetch buf
#pragma unroll
    for (int i = 0; i < 4; ++i) {
      gl_lds16(gk[i] + (size_t)nxt * HDIM, lk[i] + sOff);
      gl_lds16(gv[i] + nxt, lv[i] + sOff);
    }
    __builtin_amdgcn_sched_barrier(0);
    // Wait only for the PREVIOUS tile's 8 loads; this tile's 8 stay in
    // flight across the barrier (T4: never drain vmcnt to 0 in the loop).
    asm volatile("s_waitcnt vmcnt(8)" ::: "memory");
    __builtin_amdgcn_s_barrier();

    const int kOff = cb * 8192;                // ushort offsets, current buf
    const int vOff = cb * 8192;

#pragma unroll
    for (int sub = 0; sub < 2; ++sub) {
      const int koff = sub * 64;

      // S^T = K·Q^T: A[m=key][k=d] from Ks (swizzled b128), B = qa regs.
      // Each ka read feeds BOTH query groups (2 MFMAs per read).
      floatx16 stA0 = {}, stA1 = {}, stB0 = {}, stB1 = {};
      __builtin_amdgcn_s_setprio(1);
#pragma unroll
      for (int ds = 0; ds < 4; ++ds) {
        const int g = ds * 2 + h2;
        const int k0 = koff + q31;
        short8 ka0 = *(const short8*)&Ks[kOff + k0 * 64 + ((g ^ (q31 & 7)) * 8)];
        stA0 = __builtin_amdgcn_mfma_f32_32x32x16_bf16(ka0, qaA[ds], stA0, 0, 0, 0);
        stB0 = __builtin_amdgcn_mfma_f32_32x32x16_bf16(ka0, qaB[ds], stB0, 0, 0, 0);
        const int k1 = koff + 32 + q31;
        short8 ka1 = *(const short8*)&Ks[kOff + k1 * 64 + ((g ^ (q31 & 7)) * 8)];
        stA1 = __builtin_amdgcn_mfma_f32_32x32x16_bf16(ka1, qaA[ds], stA1, 0, 0, 0);
        stB1 = __builtin_amdgcn_mfma_f32_32x32x16_bf16(ka1, qaB[ds], stB1, 0, 0, 0);
      }
      __builtin_amdgcn_s_setprio(0);

      // P^T = exp2(S^T), fused exp+pack (short live ranges). All of a
      // lane's regs belong to its own query (col=q31) -> plain fp32 sum.
      unsigned pkA0[8], pkA1[8], pkB0[8], pkB1[8];
#pragma unroll
      for (int i = 0; i < 8; ++i) {
        float a0 = EXP2(stA0[2 * i]), b0 = EXP2(stA0[2 * i + 1]);
        float a1 = EXP2(stA1[2 * i]), b1 = EXP2(stA1[2 * i + 1]);
        laccA += (a0 + b0) + (a1 + b1);
        pkA0[i] = pack2bf(a0, b0);
        pkA1[i] = pack2bf(a1, b1);
        float c0 = EXP2(stB0[2 * i]), d0 = EXP2(stB0[2 * i + 1]);
        float c1 = EXP2(stB1[2 * i]), d1 = EXP2(stB1[2 * i + 1]);
        laccB += (c0 + d0) + (c1 + d1);
        pkB0[i] = pack2bf(c0, d0);
        pkB1[i] = pack2bf(c1, d1);
      }

      // PV: O^T += V^T·P^T, 4 k-steps of 16 keys (32x32x16 MFMA, full
      // rate). B-frag: lane needs keys ks+h2*8..+7 of its query; own regs
      // hold keys (r&3)+8*(r>>2)+4*h2 -> permlane32_swap(p[0],p[2])
      // yields B regs {0,2}, swap(p[1],p[3]) yields {1,3}.
      __builtin_amdgcn_s_setprio(1);
#pragma unroll
      for (int sp = 0; sp < 4; ++sp) {
        const unsigned* pA = (sp < 2) ? pkA0 : pkA1;
        const unsigned* pB = (sp < 2) ? pkB0 : pkB1;
        const int off = (sp & 1) * 4;
        uint2v ra0 = pl32swap(pA[off + 0], pA[off + 2]);
        uint2v ra1 = pl32swap(pA[off + 1], pA[off + 3]);
        uint2v rb0 = pl32swap(pB[off + 0], pB[off + 2]);
        uint2v rb1 = pl32swap(pB[off + 1], pB[off + 3]);
        union { unsigned u[4]; short8 v; } pbA, pbB;
        pbA.u[0] = ra0[0]; pbA.u[1] = ra1[0]; pbA.u[2] = ra0[1]; pbA.u[3] = ra1[1];
        pbB.u[0] = rb0[0]; pbB.u[1] = rb1[0]; pbB.u[2] = rb0[1]; pbB.u[3] = rb1[1];

        const int g8 = sub * 8 + sp * 2 + h2;  // global 8-key group
        const int pos = (g8 ^ (q31 & 15)) * 8;
        short8 va0 = *(const short8*)&Vs[vOff + q31 * 128 + pos];
        otA0 = __builtin_amdgcn_mfma_f32_32x32x16_bf16(va0, pbA.v, otA0, 0, 0, 0);
        otB0 = __builtin_amdgcn_mfma_f32_32x32x16_bf16(va0, pbB.v, otB0, 0, 0, 0);
        short8 va1 = *(const short8*)&Vs[vOff + (32 + q31) * 128 + pos];
        otA1 = __builtin_amdgcn_mfma_f32_32x32x16_bf16(va1, pbA.v, otA1, 0, 0, 0);
        otB1 = __builtin_amdgcn_mfma_f32_32x32x16_bf16(va1, pbB.v, otB1, 0, 0, 0);
      }
      __builtin_amdgcn_s_setprio(0);
    }

    __builtin_amdgcn_sched_barrier(0);
    __builtin_amdgcn_s_barrier();   // all waves done reading buf[cb]; next
                                    // iter's prefetch may overwrite it
  }
  asm volatile("s_waitcnt vmcnt(0)" ::: "memory");  // drain stray prefetch

  // Combine the two lane-halves' partial sums for each query group.
  const float totA = laccA + __shfl_xor(laccA, 32);
  const float totB = laccB + __shfl_xor(laccB, 32);
  const float invA = 1.0f / totA;
  const float invB = 1.0f / totB;

  // O^T C-layout: col=q (lane), row=d=(reg&3)+8*(reg>>2)+4*h2 (+32 for *1).
  const int b = bh >> 4, hh = bh & 15;
  unsigned short* orowA =
      aout + ((size_t)b * SEQ + qBase + w * 64 + q31) * EMBED + hh * HDIM;
  unsigned short* orowB = orowA + (size_t)32 * EMBED;
#pragma unroll
  for (int rg = 0; rg < 4; ++rg) {
    const int d0 = rg * 8 + h2 * 4;
    ushort4 p0, p1;
    p0.x = f2bf(otA0[4 * rg + 0] * invA); p0.y = f2bf(otA0[4 * rg + 1] * invA);
    p0.z = f2bf(otA0[4 * rg + 2] * invA); p0.w = f2bf(otA0[4 * rg + 3] * invA);
    *(ushort4*)(orowA + d0) = p0;
    p1.x = f2bf(otA1[4 * rg + 0] * invA); p1.y = f2bf(otA1[4 * rg + 1] * invA);
    p1.z = f2bf(otA1[4 * rg + 2] * invA); p1.w = f2bf(otA1[4 * rg + 3] * invA);
    *(ushort4*)(orowA + 32 + d0) = p1;
    ushort4 p2, p3;
    p2.x = f2bf(otB0[4 * rg + 0] * invB); p2.y = f2bf(otB0[4 * rg + 1] * invB);
    p2.z = f2bf(otB0[4 * rg + 2] * invB); p2.w = f2bf(otB0[4 * rg + 3] * invB);
    *(ushort4*)(orowB + d0) = p2;
    p3.x = f2bf(otB1[4 * rg + 0] * invB); p3.y = f2bf(otB1[4 * rg + 1] * invB);
    p3.z = f2bf(otB1[4 * rg + 2] * invB); p3.w = f2bf(otB1[4 * rg + 3] * invB);
    *(ushort4*)(orowB + 32 + d0) = p3;
  }
}

// ---------------------------------------------------------------------------
// Output projection (8-phase core): fp32 result straight from accumulators.
// ---------------------------------------------------------------------------
__global__ __launch_bounds__(512, 2) void out_proj_bf16(
    const unsigned short* __restrict__ aout,
    const unsigned short* __restrict__ wb,
    float* __restrict__ Cout) {
  const int id = blockIdx.x;                 // 0..127
  const int xcd = id & 7;
  const int r = id >> 3;                     // 0..15
  const int nBase = (r >> 2) * 256;
  const int mBase = (xcd * 4 + (r & 3)) * 256;

  __shared__ unsigned short LA[32768];
  __shared__ unsigned short LB[32768];

  floatx4 acc[8][4] = {};
  gemm_core8(aout, wb + ((size_t)3 << 20), mBase, nBase, LA, LB, acc);

  const int t = threadIdx.x;
  const int lane = t & 63, wv = t >> 6;
  const int wr = wv >> 2, wc = wv & 3;
  const int quad = lane >> 4, l15 = lane & 15;

#pragma unroll
  for (int mi = 0; mi < 8; ++mi)
#pragma unroll
    for (int ni = 0; ni < 4; ++ni) {
      const int n = nBase + wc * 64 + ni * 16 + l15;
#pragma unroll
      for (int r2 = 0; r2 < 4; ++r2) {
        const int m = mBase + wr * 128 + mi * 16 + quad * 4 + r2;
        Cout[(size_t)m * EMBED + n] = acc[mi][ni][r2];
      }
    }
}

extern "C" void kernel_launch(void* const* d_in, const int* in_sizes, int n_in,
                              void* d_out, int out_size, void* d_ws, size_t ws_size,
                              hipStream_t stream) {
  const float* x  = (const float*)d_in[0];
  const float* wq = (const float*)d_in[1];
  const float* wk = (const float*)d_in[2];
  const float* wv = (const float*)d_in[3];
  const float* wo = (const float*)d_in[4];
  float* out = (float*)d_out;

  char* ws = (char*)d_ws;
  unsigned short* xb   = (unsigned short*)(ws);                  // 16.8 MB
  unsigned short* wb   = (unsigned short*)(ws + (16u << 20));    // 8.4 MB
  unsigned short* qkv  = (unsigned short*)(ws + (26u << 20));    // 50.3 MB
  unsigned short* aout = (unsigned short*)(ws + (76u << 20));    // 16.8 MB

  cast_bf16_kernel<<<12288, 256, 0, stream>>>(x, wq, wk, wv, wo, xb, wb);
  proj_qkv_bf16<<<384, 512, 0, stream>>>(xb, wb, qkv);
  attn_mfma<<<512, 256, 0, stream>>>(qkv, aout);
  out_proj_bf16<<<128, 512, 0, stream>>>(aout, wb, out);
}

// Round 12
// 265.661 us; speedup vs baseline: 1.0243x; 1.0243x over previous
//
#include <hip/hip_runtime.h>
#include <math.h>

#define EMBED 1024
#define NHEAD 16
#define HDIM  64
#define BATCH 4
#define SEQ   2048
#define MROWS (BATCH * SEQ)   // 8192

typedef __attribute__((ext_vector_type(4))) short short4v;
typedef __attribute__((ext_vector_type(8))) short short8;
typedef __attribute__((ext_vector_type(4))) float floatx4;
typedef __attribute__((ext_vector_type(16))) float floatx16;
typedef __attribute__((ext_vector_type(2))) unsigned uint2v;

#if __has_builtin(__builtin_amdgcn_exp2f)
#define EXP2(x) __builtin_amdgcn_exp2f(x)
#else
#define EXP2(x) exp2f(x)
#endif

// RNE float -> bf16 (finite inputs only).
__device__ __forceinline__ unsigned short f2bf(float f) {
  unsigned u = __float_as_uint(f);
  u += 0x7fffu + ((u >> 16) & 1u);
  return (unsigned short)(u >> 16);
}

#if __has_builtin(__builtin_amdgcn_cvt_pk_bf16_f32)
__device__ __forceinline__ unsigned pack2bf(float lo, float hi) {
  typedef __attribute__((ext_vector_type(2))) __bf16 bf2;
  union { bf2 b; unsigned u; } c;
  c.b = __builtin_amdgcn_cvt_pk_bf16_f32(lo, hi);
  return c.u;
}
#else
__device__ __forceinline__ unsigned pack2bf(float lo, float hi) {
  return ((__float_as_uint(lo) + 0x8000u) >> 16) |
         ((__float_as_uint(hi) + 0x8000u) & 0xffff0000u);
}
#endif

__device__ __forceinline__ uint2v pl32swap(unsigned a, unsigned b) {
#if __has_builtin(__builtin_amdgcn_permlane32_swap)
  return __builtin_amdgcn_permlane32_swap(a, b, false, false);
#else
  uint2v r;
  unsigned ax = (unsigned)__shfl_xor((int)a, 32);
  unsigned bx = (unsigned)__shfl_xor((int)b, 32);
  const int hi = (int)((threadIdx.x & 63) >> 5);
  r[0] = hi ? bx : a;
  r[1] = hi ? b : ax;
  return r;
#endif
}

// Async global->LDS, 16 B per lane. lds dest MUST be wave-uniform base;
// HW adds lane*16.
__device__ __forceinline__ void gl_lds16(const void* g, void* l) {
  __builtin_amdgcn_global_load_lds(
      (const __attribute__((address_space(1))) unsigned int*)g,
      (__attribute__((address_space(3))) unsigned int*)l, 16, 0, 0);
}

// ---------------------------------------------------------------------------
// Cast fp32 -> bf16: x (8M elems) + 4 weights (1M each, contiguous dst).
// ---------------------------------------------------------------------------
__global__ __launch_bounds__(256) void cast_bf16_kernel(
    const float* __restrict__ x,  const float* __restrict__ wq,
    const float* __restrict__ wk, const float* __restrict__ wv,
    const float* __restrict__ wo,
    unsigned short* __restrict__ xb, unsigned short* __restrict__ wb) {
  const size_t NX = (size_t)MROWS * EMBED;                 // 2^23
  size_t i4 = ((size_t)blockIdx.x * 256 + threadIdx.x) * 4;
  const float* src;
  unsigned short* dst;
  size_t off;
  if (i4 < NX) {
    src = x; dst = xb; off = i4;
  } else {
    size_t j = i4 - NX;
    int r = (int)(j >> 20);
    off = j & ((1u << 20) - 1);
    src = (r == 0) ? wq : (r == 1) ? wk : (r == 2) ? wv : wo;
    dst = wb + ((size_t)r << 20);
  }
  float4 v = *(const float4*)(src + off);
  ushort4 o;
  o.x = f2bf(v.x); o.y = f2bf(v.y); o.z = f2bf(v.z); o.w = f2bf(v.w);
  *(ushort4*)(dst + off) = o;
}

// ---------------------------------------------------------------------------
// R19: 256x128 8-phase bf16 GEMM core. R18's 256x256 was perf-neutral:
// grid quantization (proj 384 blocks = 1.5 rounds of 256 CUs @1 block/CU;
// out_proj 128 blocks = HALF the chip idle) cancelled the schedule gain.
// 256x128 tile -> proj 768 blocks = 3.0 exact rounds, out_proj 256 = 1.0.
// 8 waves (2Mx4N), per-wave 128x32, BK=64, LDS 96KB: A 2buf x 2half x
// [128][64] (64KB) + B 2buf x [128][64] (32KB). Per 2-tile iteration,
// 8 phases; stage plan (FIFO/WAR hand-verified):
//   p0: A(T+1)h0 + gate vmcnt(4)   p1: A(T+1)h1   p2: B(T+2)   p3: -
//   p4: A(T+2)h0 + gate vmcnt(4)   p5: A(T+2)h1   p6: B(T+3)   p7: -
// Prologue stages A(0)(4),B(0)(2),B(1)(2); gate retires exactly the tile
// about to be read (6 loads), keeps 4 in flight. XOR-8 16B-group swizzle
// rows (write via pre-swizzled global source, read with same XOR).
// ---------------------------------------------------------------------------
#define RD_A(bo, mi, ks) (*(const short8*)&LA[(bo) + wr * 8192 + \
    ((mi) * 16 + l15) * 64 + ((((ks) * 4 + quad) ^ (l15 & 7)) * 8)])
#define RD_B(boB, ni, ks) (*(const short8*)&LB[(boB) + \
    (rB0 + (ni) * 16 + l15) * 64 + ((((ks) * 4 + quad) ^ (l15 & 7)) * 8)])

__device__ __forceinline__ void gemm_core8(
    const unsigned short* __restrict__ Amat,
    const unsigned short* __restrict__ Bmat,
    int mBase, int nBase,
    unsigned short* LA, unsigned short* LB,
    floatx4 acc[8][2]) {
  const int t = threadIdx.x;                 // 0..511
  const int lane = t & 63, wv = t >> 6;      // 8 waves
  const int wr = wv >> 2, wc = wv & 3;
  const int quad = lane >> 4, l15 = lane & 15;
  const int rB0 = wc * 32;

  // Staging addresses. Chunk c = i*512 + t covers LDS bytes [c*16,c*16+16)
  // of a half-tile; stored 16B-group (c&7) holds logical group
  // (c&7)^(row&7) -> pre-swizzled global source, linear LDS dest.
  const unsigned short* sA[2][2];
  const unsigned short* sB[2];
  unsigned short* dA[2][2];
  unsigned short* dB[2];
#pragma unroll
  for (int i = 0; i < 2; ++i) {
    const int c = i * 512 + t;
    const int row = c >> 3, g = (c & 7) ^ (row & 7);
    sA[0][i] = Amat + (size_t)(mBase + row) * EMBED + g * 8;
    sA[1][i] = Amat + (size_t)(mBase + 128 + row) * EMBED + g * 8;
    sB[i]    = Bmat + (size_t)(nBase + row) * EMBED + g * 8;
    const int du = (i * 512 + wv * 64) * 8;  // wave-uniform dest base
    dA[0][i] = LA + du;
    dA[1][i] = LA + 8192 + du;
    dB[i]    = LB + du;
  }

  // Prologue: A(0) (4 loads), B(0) (2), B(1) (2) — FIFO order matters.
  gl_lds16(sA[0][0], dA[0][0]); gl_lds16(sA[0][1], dA[0][1]);
  gl_lds16(sA[1][0], dA[1][0]); gl_lds16(sA[1][1], dA[1][1]);
  gl_lds16(sB[0], dB[0]);       gl_lds16(sB[1], dB[1]);
  gl_lds16(sB[0] + 64, dB[0] + 8192);
  gl_lds16(sB[1] + 64, dB[1] + 8192);

  short8 b[2][2];
  for (int T = 0; T < 16; T += 2) {          // 8 iterations, 2 K-tiles each
#pragma unroll
    for (int hf = 0; hf < 2; ++hf) {         // tile T+hf; A buf hf, B buf hf
      const int bo = hf * 16384;
      const int boB = hf * 8192;
#pragma unroll
      for (int p = 0; p < 4; ++p) {
        short8 a[2][2];
        const int mi0 = 2 * p;
        if (p == 0) {
          // stage A(T+1+hf)h0, then gate, then read this tile's frags.
          {
            const int ts = (T + 1 + hf) & 15, tb = (ts & 1) * 16384;
            gl_lds16(sA[0][0] + (size_t)ts * 64, dA[0][0] + tb);
            gl_lds16(sA[0][1] + (size_t)ts * 64, dA[0][1] + tb);
          }
          asm volatile("s_waitcnt vmcnt(4)" ::: "memory");
          __builtin_amdgcn_sched_barrier(0);
          __builtin_amdgcn_s_barrier();      // all waves' loads retired
          b[0][0] = RD_B(boB, 0, 0); b[0][1] = RD_B(boB, 0, 1);
          b[1][0] = RD_B(boB, 1, 0); b[1][1] = RD_B(boB, 1, 1);
          a[0][0] = RD_A(bo, 0, 0); a[0][1] = RD_A(bo, 0, 1);
          a[1][0] = RD_A(bo, 1, 0); a[1][1] = RD_A(bo, 1, 1);
        } else {
          a[0][0] = RD_A(bo, mi0, 0);     a[0][1] = RD_A(bo, mi0, 1);
          a[1][0] = RD_A(bo, mi0 + 1, 0); a[1][1] = RD_A(bo, mi0 + 1, 1);
          if (p == 1) {
            const int ts = (T + 1 + hf) & 15, tb = (ts & 1) * 16384;
            gl_lds16(sA[1][0] + (size_t)ts * 64, dA[1][0] + tb);
            gl_lds16(sA[1][1] + (size_t)ts * 64, dA[1][1] + tb);
          } else if (p == 2) {
            const int ts = (T + 2 + hf) & 15, tbB = (ts & 1) * 8192;
            gl_lds16(sB[0] + (size_t)ts * 64, dB[0] + tbB);
            gl_lds16(sB[1] + (size_t)ts * 64, dB[1] + tbB);
          }
          __builtin_amdgcn_sched_barrier(0);
          __builtin_amdgcn_s_barrier();
        }
        asm volatile("s_waitcnt lgkmcnt(0)" ::: "memory");
        __builtin_amdgcn_sched_barrier(0);
        __builtin_amdgcn_s_setprio(1);
#pragma unroll
        for (int m2 = 0; m2 < 2; ++m2)
#pragma unroll
          for (int ni = 0; ni < 2; ++ni) {
            acc[mi0 + m2][ni] = __builtin_amdgcn_mfma_f32_16x16x32_bf16(
                a[m2][0], b[ni][0], acc[mi0 + m2][ni], 0, 0, 0);
            acc[mi0 + m2][ni] = __builtin_amdgcn_mfma_f32_16x16x32_bf16(
                a[m2][1], b[ni][1], acc[mi0 + m2][ni], 0, 0, 0);
          }
        __builtin_amdgcn_s_setprio(0);
        __builtin_amdgcn_sched_barrier(0);
        __builtin_amdgcn_s_barrier();        // frees this phase's WAR slot
      }
    }
  }
  asm volatile("s_waitcnt vmcnt(0)" ::: "memory");  // drain wrapped stages
}

// ---------------------------------------------------------------------------
// QKV projection as ONE GEMM: A[8192,1024] @ Wstack[3072,1024]^T. Q
// pre-scaled by (1/8)*log2(e). Q,K out: [b,h,s,d]; V out: [b,h,d,s].
// 768 blocks = 3.0 exact rounds; bijective XCD decode (per-XCD A chunk
// 4 mTiles = 2MB, L2-resident, swept over all 24 nTiles).
// ---------------------------------------------------------------------------
__global__ __launch_bounds__(512, 2) void proj_qkv_bf16(
    const unsigned short* __restrict__ xb,
    const unsigned short* __restrict__ wb,
    unsigned short* __restrict__ qkv) {
  const int id = blockIdx.x;                 // 0..767
  const int xcd = id & 7;
  const int r = id >> 3;                     // 0..95
  const int nIdx = r >> 2;                   // 0..23
  const int mBase = (xcd * 4 + (r & 3)) * 256;
  const int nBase = nIdx * 128;

  __shared__ unsigned short LA[32768];       // 64 KB
  __shared__ unsigned short LB[16384];       // 32 KB

  floatx4 acc[8][2] = {};
  gemm_core8(xb, wb, mBase, nBase, LA, LB, acc);

  const int t = threadIdx.x;
  const int lane = t & 63, wv = t >> 6;
  const int wr = wv >> 2, wc = wv & 3;
  const int quad = lane >> 4, l15 = lane & 15;

  const int which = nBase >> 10;             // uniform per block
  const int nloc0 = nBase & 1023;
  unsigned short* out = qkv + (size_t)which * MROWS * EMBED;

  if (which < 2) {
    const float scale = (which == 0) ? 0.18033688f : 1.0f;  // (1/8)*log2(e)
#pragma unroll
    for (int mi = 0; mi < 8; ++mi)
#pragma unroll
      for (int ni = 0; ni < 2; ++ni) {
        const int nn = nloc0 + wc * 32 + ni * 16 + l15;
        const int h = nn >> 6, d = nn & 63;
#pragma unroll
        for (int r2 = 0; r2 < 4; ++r2) {
          const int m = mBase + wr * 128 + mi * 16 + quad * 4 + r2;
          const int b = m >> 11, s = m & (SEQ - 1);
          out[(((size_t)(b * NHEAD + h) * SEQ) + s) * HDIM + d] =
              f2bf(acc[mi][ni][r2] * scale);
        }
      }
  } else {
    // V^T: [b,h,d,s] — 4 consecutive s per lane -> packed 8 B store.
#pragma unroll
    for (int mi = 0; mi < 8; ++mi) {
      const int m0 = mBase + wr * 128 + mi * 16 + quad * 4;
      const int b = m0 >> 11, s0 = m0 & (SEQ - 1);
#pragma unroll
      for (int ni = 0; ni < 2; ++ni) {
        const int nn = nloc0 + wc * 32 + ni * 16 + l15;
        const int h = nn >> 6, d = nn & 63;
        ushort4 pk;
        pk.x = f2bf(acc[mi][ni][0]); pk.y = f2bf(acc[mi][ni][1]);
        pk.z = f2bf(acc[mi][ni][2]); pk.w = f2bf(acc[mi][ni][3]);
        *(ushort4*)&out[((size_t)(b * NHEAD + h) * HDIM + d) * SEQ + s0] = pk;
      }
    }
  }
}

// ---------------------------------------------------------------------------
// MFMA flash attention, transposed-score formulation.
// = R12 structure (best measured: 85.6-87.0us). R13 (interleave), R14
// (domain decorrelation) and R15 (split-K, cache collapse) all failed to
// beat it — phase-separated 2-blocks/CU with KVBLK=128 is the optimum.
// ---------------------------------------------------------------------------
__global__ __launch_bounds__(256, 2) void attn_mfma(
    const unsigned short* __restrict__ qkv,
    unsigned short* __restrict__ aout) {
  const unsigned short* Q = qkv;
  const unsigned short* K = qkv + (size_t)MROWS * EMBED;
  const unsigned short* V = qkv + 2 * (size_t)MROWS * EMBED;

  // XCD-locality decode: all 8 q-blocks of one bh land on one XCD.
  const int id = blockIdx.x;
  const int xcd = id & 7, slot = id >> 3;      // slot 0..63
  const int bh = xcd * 8 + (slot >> 3);
  const int qBase = (slot & 7) * 256;

  __shared__ unsigned short Ks[2 * 128 * 64];  // [buf][key][d], XOR-8 swizzled
  __shared__ unsigned short Vs[2 * 64 * 128];  // [buf][d][key], XOR-16 swizzled

  const int t = threadIdx.x;
  const int lane = t & 63, w = t >> 6;         // w 0..3
  const int h2 = lane >> 5;     // lane half (k-group selector in A/B frags)
  const int q31 = lane & 31;    // query within group / col within MFMA tile

  // Q B-frags (pre-scaled by (1/8)*log2e): B[k=d][n=q]. Two query groups.
  const unsigned short* qrowA =
      Q + ((size_t)bh * SEQ + qBase + w * 64 + q31) * HDIM;
  const unsigned short* qrowB = qrowA + 32 * HDIM;
  short8 qaA[4], qaB[4];
#pragma unroll
  for (int ds = 0; ds < 4; ++ds) {
    qaA[ds] = *(const short8*)(qrowA + ds * 16 + h2 * 8);
    qaB[ds] = *(const short8*)(qrowB + ds * 16 + h2 * 8);
  }

  // Staging: 256 threads stage 16 KB K + 16 KB V per tile -> 4 K-chunks +
  // 4 V-chunks of 16 B per thread (8 gl_lds per tile).
  const unsigned short* kbase = K + (size_t)bh * SEQ * HDIM;
  const unsigned short* vbase = V + (size_t)bh * HDIM * SEQ;
  const unsigned short* gk[4];
  const unsigned short* gv[4];
  unsigned short* lk[4];
  unsigned short* lv[4];
#pragma unroll
  for (int i = 0; i < 4; ++i) {
    const int c = i * 256 + t;                 // per-lane chunk 0..1023
    const int krow = c >> 3, kgrp = (c & 7) ^ (krow & 7);
    gk[i] = kbase + (size_t)krow * HDIM + kgrp * 8;
    const int vd = c >> 4, vj = (c & 15) ^ (vd & 15);
    gv[i] = vbase + (size_t)vd * SEQ + vj * 8;
    const int cu = i * 256 + w * 64;           // wave-uniform chunk base
    lk[i] = Ks + cu * 8;
    lv[i] = Vs + cu * 8;
  }

  floatx16 otA0 = {}, otA1 = {};  // group A O^T accum: d 0-31, 32-63
  floatx16 otB0 = {}, otB1 = {};  // group B
  float laccA = 0.0f, laccB = 0.0f;

  // Prologue: stage tile 0 into buffer 0.
#pragma unroll
  for (int i = 0; i < 4; ++i) {
    gl_lds16(gk[i], lk[i]);
    gl_lds16(gv[i], lv[i]);
  }

  for (int kt = 0; kt < SEQ; kt += 128) {
    const int cb = (kt >> 7) & 1;              // current buffer
    const int nb = cb ^ 1;                     // prefetch buffer
    const int nxt = (kt + 128) & (SEQ - 1);    // last iter re-stages tile 0
                                               // (keeps vmcnt count uniform)
    const int sOff = nb * 8192;                // ushort offset of prefetch buf
#pragma unroll
    for (int i = 0; i < 4; ++i) {
      gl_lds16(gk[i] + (size_t)nxt * HDIM, lk[i] + sOff);
      gl_lds16(gv[i] + nxt, lv[i] + sOff);
    }
    __builtin_amdgcn_sched_barrier(0);
    // Wait only for the PREVIOUS tile's 8 loads; this tile's 8 stay in
    // flight across the barrier (T4: never drain vmcnt to 0 in the loop).
    asm volatile("s_waitcnt vmcnt(8)" ::: "memory");
    __builtin_amdgcn_s_barrier();

    const int kOff = cb * 8192;                // ushort offsets, current buf
    const int vOff = cb * 8192;

#pragma unroll
    for (int sub = 0; sub < 2; ++sub) {
      const int koff = sub * 64;

      // S^T = K·Q^T: A[m=key][k=d] from Ks (swizzled b128), B = qa regs.
      // Each ka read feeds BOTH query groups (2 MFMAs per read).
      floatx16 stA0 = {}, stA1 = {}, stB0 = {}, stB1 = {};
      __builtin_amdgcn_s_setprio(1);
#pragma unroll
      for (int ds = 0; ds < 4; ++ds) {
        const int g = ds * 2 + h2;
        const int k0 = koff + q31;
        short8 ka0 = *(const short8*)&Ks[kOff + k0 * 64 + ((g ^ (q31 & 7)) * 8)];
        stA0 = __builtin_amdgcn_mfma_f32_32x32x16_bf16(ka0, qaA[ds], stA0, 0, 0, 0);
        stB0 = __builtin_amdgcn_mfma_f32_32x32x16_bf16(ka0, qaB[ds], stB0, 0, 0, 0);
        const int k1 = koff + 32 + q31;
        short8 ka1 = *(const short8*)&Ks[kOff + k1 * 64 + ((g ^ (q31 & 7)) * 8)];
        stA1 = __builtin_amdgcn_mfma_f32_32x32x16_bf16(ka1, qaA[ds], stA1, 0, 0, 0);
        stB1 = __builtin_amdgcn_mfma_f32_32x32x16_bf16(ka1, qaB[ds], stB1, 0, 0, 0);
      }
      __builtin_amdgcn_s_setprio(0);

      // P^T = exp2(S^T), fused exp+pack (short live ranges). All of a
      // lane's regs belong to its own query (col=q31) -> plain fp32 sum.
      unsigned pkA0[8], pkA1[8], pkB0[8], pkB1[8];
#pragma unroll
      for (int i = 0; i < 8; ++i) {
        float a0 = EXP2(stA0[2 * i]), b0 = EXP2(stA0[2 * i + 1]);
        float a1 = EXP2(stA1[2 * i]), b1 = EXP2(stA1[2 * i + 1]);
        laccA += (a0 + b0) + (a1 + b1);
        pkA0[i] = pack2bf(a0, b0);
        pkA1[i] = pack2bf(a1, b1);
        float c0 = EXP2(stB0[2 * i]), d0 = EXP2(stB0[2 * i + 1]);
        float c1 = EXP2(stB1[2 * i]), d1 = EXP2(stB1[2 * i + 1]);
        laccB += (c0 + d0) + (c1 + d1);
        pkB0[i] = pack2bf(c0, d0);
        pkB1[i] = pack2bf(c1, d1);
      }

      // PV: O^T += V^T·P^T, 4 k-steps of 16 keys (32x32x16 MFMA, full
      // rate). B-frag: lane needs keys ks+h2*8..+7 of its query; own regs
      // hold keys (r&3)+8*(r>>2)+4*h2 -> permlane32_swap(p[0],p[2])
      // yields B regs {0,2}, swap(p[1],p[3]) yields {1,3}.
      __builtin_amdgcn_s_setprio(1);
#pragma unroll
      for (int sp = 0; sp < 4; ++sp) {
        const unsigned* pA = (sp < 2) ? pkA0 : pkA1;
        const unsigned* pB = (sp < 2) ? pkB0 : pkB1;
        const int off = (sp & 1) * 4;
        uint2v ra0 = pl32swap(pA[off + 0], pA[off + 2]);
        uint2v ra1 = pl32swap(pA[off + 1], pA[off + 3]);
        uint2v rb0 = pl32swap(pB[off + 0], pB[off + 2]);
        uint2v rb1 = pl32swap(pB[off + 1], pB[off + 3]);
        union { unsigned u[4]; short8 v; } pbA, pbB;
        pbA.u[0] = ra0[0]; pbA.u[1] = ra1[0]; pbA.u[2] = ra0[1]; pbA.u[3] = ra1[1];
        pbB.u[0] = rb0[0]; pbB.u[1] = rb1[0]; pbB.u[2] = rb0[1]; pbB.u[3] = rb1[1];

        const int g8 = sub * 8 + sp * 2 + h2;  // global 8-key group
        const int pos = (g8 ^ (q31 & 15)) * 8;
        short8 va0 = *(const short8*)&Vs[vOff + q31 * 128 + pos];
        otA0 = __builtin_amdgcn_mfma_f32_32x32x16_bf16(va0, pbA.v, otA0, 0, 0, 0);
        otB0 = __builtin_amdgcn_mfma_f32_32x32x16_bf16(va0, pbB.v, otB0, 0, 0, 0);
        short8 va1 = *(const short8*)&Vs[vOff + (32 + q31) * 128 + pos];
        otA1 = __builtin_amdgcn_mfma_f32_32x32x16_bf16(va1, pbA.v, otA1, 0, 0, 0);
        otB1 = __builtin_amdgcn_mfma_f32_32x32x16_bf16(va1, pbB.v, otB1, 0, 0, 0);
      }
      __builtin_amdgcn_s_setprio(0);
    }

    __builtin_amdgcn_sched_barrier(0);
    __builtin_amdgcn_s_barrier();   // all waves done reading buf[cb]; next
                                    // iter's prefetch may overwrite it
  }
  asm volatile("s_waitcnt vmcnt(0)" ::: "memory");  // drain stray prefetch

  // Combine the two lane-halves' partial sums for each query group.
  const float totA = laccA + __shfl_xor(laccA, 32);
  const float totB = laccB + __shfl_xor(laccB, 32);
  const float invA = 1.0f / totA;
  const float invB = 1.0f / totB;

  // O^T C-layout: col=q (lane), row=d=(reg&3)+8*(reg>>2)+4*h2 (+32 for *1).
  const int b = bh >> 4, hh = bh & 15;
  unsigned short* orowA =
      aout + ((size_t)b * SEQ + qBase + w * 64 + q31) * EMBED + hh * HDIM;
  unsigned short* orowB = orowA + (size_t)32 * EMBED;
#pragma unroll
  for (int rg = 0; rg < 4; ++rg) {
    const int d0 = rg * 8 + h2 * 4;
    ushort4 p0, p1;
    p0.x = f2bf(otA0[4 * rg + 0] * invA); p0.y = f2bf(otA0[4 * rg + 1] * invA);
    p0.z = f2bf(otA0[4 * rg + 2] * invA); p0.w = f2bf(otA0[4 * rg + 3] * invA);
    *(ushort4*)(orowA + d0) = p0;
    p1.x = f2bf(otA1[4 * rg + 0] * invA); p1.y = f2bf(otA1[4 * rg + 1] * invA);
    p1.z = f2bf(otA1[4 * rg + 2] * invA); p1.w = f2bf(otA1[4 * rg + 3] * invA);
    *(ushort4*)(orowA + 32 + d0) = p1;
    ushort4 p2, p3;
    p2.x = f2bf(otB0[4 * rg + 0] * invB); p2.y = f2bf(otB0[4 * rg + 1] * invB);
    p2.z = f2bf(otB0[4 * rg + 2] * invB); p2.w = f2bf(otB0[4 * rg + 3] * invB);
    *(ushort4*)(orowB + d0) = p2;
    p3.x = f2bf(otB1[4 * rg + 0] * invB); p3.y = f2bf(otB1[4 * rg + 1] * invB);
    p3.z = f2bf(otB1[4 * rg + 2] * invB); p3.w = f2bf(otB1[4 * rg + 3] * invB);
    *(ushort4*)(orowB + 32 + d0) = p3;
  }
}

// ---------------------------------------------------------------------------
// Output projection (256x128 8-phase core): fp32 result from accumulators.
// 256 blocks = 1.0 exact round (R18's 128 blocks left HALF the chip idle).
// ---------------------------------------------------------------------------
__global__ __launch_bounds__(512, 2) void out_proj_bf16(
    const unsigned short* __restrict__ aout,
    const unsigned short* __restrict__ wb,
    float* __restrict__ Cout) {
  const int id = blockIdx.x;                 // 0..255
  const int xcd = id & 7;
  const int r = id >> 3;                     // 0..31
  const int nBase = (r >> 2) * 128;
  const int mBase = (xcd * 4 + (r & 3)) * 256;

  __shared__ unsigned short LA[32768];
  __shared__ unsigned short LB[16384];

  floatx4 acc[8][2] = {};
  gemm_core8(aout, wb + ((size_t)3 << 20), mBase, nBase, LA, LB, acc);

  const int t = threadIdx.x;
  const int lane = t & 63, wv = t >> 6;
  const int wr = wv >> 2, wc = wv & 3;
  const int quad = lane >> 4, l15 = lane & 15;

#pragma unroll
  for (int mi = 0; mi < 8; ++mi)
#pragma unroll
    for (int ni = 0; ni < 2; ++ni) {
      const int n = nBase + wc * 32 + ni * 16 + l15;
#pragma unroll
      for (int r2 = 0; r2 < 4; ++r2) {
        const int m = mBase + wr * 128 + mi * 16 + quad * 4 + r2;
        Cout[(size_t)m * EMBED + n] = acc[mi][ni][r2];
      }
    }
}

extern "C" void kernel_launch(void* const* d_in, const int* in_sizes, int n_in,
                              void* d_out, int out_size, void* d_ws, size_t ws_size,
                              hipStream_t stream) {
  const float* x  = (const float*)d_in[0];
  const float* wq = (const float*)d_in[1];
  const float* wk = (const float*)d_in[2];
  const float* wv = (const float*)d_in[3];
  const float* wo = (const float*)d_in[4];
  float* out = (float*)d_out;

  char* ws = (char*)d_ws;
  unsigned short* xb   = (unsigned short*)(ws);                  // 16.8 MB
  unsigned short* wb   = (unsigned short*)(ws + (16u << 20));    // 8.4 MB
  unsigned short* qkv  = (unsigned short*)(ws + (26u << 20));    // 50.3 MB
  unsigned short* aout = (unsigned short*)(ws + (76u << 20));    // 16.8 MB

  cast_bf16_kernel<<<12288, 256, 0, stream>>>(x, wq, wk, wv, wo, xb, wb);
  proj_qkv_bf16<<<768, 512, 0, stream>>>(xb, wb, qkv);
  attn_mfma<<<512, 256, 0, stream>>>(qkv, aout);
  out_proj_bf16<<<256, 512, 0, stream>>>(aout, wb, out);
}